// Round 16
// baseline (108.629 us; speedup 1.0000x reference)
//
#include <hip/hip_runtime.h>

typedef float v2f __attribute__((ext_vector_type(2)));
typedef float v4f __attribute__((ext_vector_type(4)));

#define W 1024
#define H 1024
#define NB 16
#define TX 32
#define TY 18
#define HR 24               // TY + 6 h-conv rows per block
#define NTH 192             // 3 waves
#define YBLK ((H + TY - 1) / TY)   // 57 (last block 2 rows OOB, guarded)
#define QSTRIDE 128         // dwords per quad segment: 32 cols x 4 ch
#define RSTRIDE 260         // dwords per h-row: 2 quads x 128 + 4 pad (bank spread)
#define NBLK (32 * YBLK * NB)      // 29184 partials = 114 * 256 exactly
#define NRED1 (NBLK / 256)         // 114 level-1 blocks

// Fused SSIM (r6 conv schedule, quad-interleaved LDS).
//   hbuf layout: [HR][2 quads][TX cols][4 ch] + 4-dword row pad.
//     quad0 = {mu1,mu2,mu3,E11}, quad1 = {E22,E33,E12,E13}.
//     B writes: b128 start bank 4(br+bc0+j) mod 32 -> 8 lanes/start = b128 floor.
//     C reads:  b128 start bank 4(r0+dy+tx) mod 32 -> balanced, throughput floor.
//   Stage B: 192 tasks = 24 rows x 8 col-groups, one per thread; weight-pair
//            m-loop kept verbatim from r6 (schedule-sensitive, r14 regressed).
//   Stage C: 32 cols x 6 rowgroups x 3-tall; 18 b128 reads (was 72 b32).
__global__ __launch_bounds__(NTH, 4) void ssim_main(
    const float* __restrict__ img1, const float* __restrict__ img2,
    const float* __restrict__ img3, const float* __restrict__ win,
    float* __restrict__ partial)
{
    __shared__ __align__(16) float hbuf[HR * RSTRIDE];  // 24960 B
    __shared__ float wavesum[3];

    const int tid = threadIdx.x;
    const int x0  = blockIdx.x * TX;
    const int ys0 = blockIdx.y * TY;
    const size_t imoff = (size_t)blockIdx.z * (size_t)(W * H);
    const float* p1 = img1 + imoff;
    const float* p2 = img2 + imoff;
    const float* p3 = img3 + imoff;

    // Separable 1-D gaussian: g[j] = win[3][j] / sqrt(win[3][3])
    float g[7];
    {
        const float inv = 1.0f / sqrtf(win[24]);
        #pragma unroll
        for (int j = 0; j < 7; ++j) g[j] = win[21 + j] * inv;
    }

    // ---- Stage B: horizontal conv, global -> LDS (1 task per thread) ----
    {
        const int br  = tid >> 3;            // 0..23  h-row within block
        const int bc0 = (tid & 7) << 2;      // 0,4,...,28
        const int gy  = ys0 + br - 3;
        const int gx0 = x0 + bc0 - 4;
        const bool xfast = (gx0 >= 0) & (gx0 + 12 <= W);

        v2f accA[8], accB[8];                // j=(0,1) and j=(2,3)
        #pragma unroll
        for (int ch = 0; ch < 8; ++ch) { accA[ch] = (v2f)0.0f; accB[ch] = (v2f)0.0f; }

        if ((gy >= 0) & (gy < H)) {
            const size_t rowoff = (size_t)gy * W;
            float V1[12], V2[12], V3[12];
            if (xfast) {
                const float* q1 = p1 + rowoff + gx0;
                const float* q2 = p2 + rowoff + gx0;
                const float* q3 = p3 + rowoff + gx0;
                *(float4*)&V1[0] = *(const float4*)(q1);
                *(float4*)&V1[4] = *(const float4*)(q1 + 4);
                *(float4*)&V1[8] = *(const float4*)(q1 + 8);
                *(float4*)&V2[0] = *(const float4*)(q2);
                *(float4*)&V2[4] = *(const float4*)(q2 + 4);
                *(float4*)&V2[8] = *(const float4*)(q2 + 8);
                *(float4*)&V3[0] = *(const float4*)(q3);
                *(float4*)&V3[4] = *(const float4*)(q3 + 4);
                *(float4*)&V3[8] = *(const float4*)(q3 + 8);
            } else {
                #pragma unroll
                for (int c = 0; c < 12; ++c) {
                    const int x = gx0 + c;
                    const bool ok = (x >= 0) & (x < W);
                    const size_t off = rowoff + x;
                    V1[c] = ok ? p1[off] : 0.0f;
                    V2[c] = ok ? p2[off] : 0.0f;
                    V3[c] = ok ? p3[off] : 0.0f;
                }
            }

            // weight-pair table: gp[m-1] = {g[m-1], g[m-2]} (edges zero-padded)
            v2f gp[8];
            gp[0] = (v2f){g[0], 0.0f};
            #pragma unroll
            for (int m = 2; m <= 7; ++m) gp[m - 1] = (v2f){g[m - 1], g[m - 2]};
            gp[7] = (v2f){0.0f, g[6]};

            #pragma unroll
            for (int m = 1; m <= 8; ++m) {
                const v2f w = gp[m - 1];
                const float vA1 = V1[m], vA2 = V2[m], vA3 = V3[m];
                const float vB1 = V1[m + 2], vB2 = V2[m + 2], vB3 = V3[m + 2];
                v2f t;
                t = w * vA1;
                accA[0] += t;
                accA[3] += t * vA1;
                accA[6] += t * vA2;
                accA[7] += t * vA3;
                t = w * vA2;
                accA[1] += t;
                accA[4] += t * vA2;
                t = w * vA3;
                accA[2] += t;
                accA[5] += t * vA3;
                t = w * vB1;
                accB[0] += t;
                accB[3] += t * vB1;
                accB[6] += t * vB2;
                accB[7] += t * vB3;
                t = w * vB2;
                accB[1] += t;
                accB[4] += t * vB2;
                t = w * vB3;
                accB[2] += t;
                accB[5] += t * vB3;
            }
        }
        // quad-interleaved write: 8x ds_write_b128
        // acc(ch, j): j0=accA[ch].x, j1=accA[ch].y, j2=accB[ch].x, j3=accB[ch].y
        const int wbase = br * RSTRIDE + bc0 * 4;
        #pragma unroll
        for (int q = 0; q < 2; ++q) {
            float* d = &hbuf[wbase + q * QSTRIDE];
            const int c0 = 4 * q;
            *(float4*)(d + 0)  = make_float4(accA[c0].x, accA[c0 + 1].x,
                                             accA[c0 + 2].x, accA[c0 + 3].x);
            *(float4*)(d + 4)  = make_float4(accA[c0].y, accA[c0 + 1].y,
                                             accA[c0 + 2].y, accA[c0 + 3].y);
            *(float4*)(d + 8)  = make_float4(accB[c0].x, accB[c0 + 1].x,
                                             accB[c0 + 2].x, accB[c0 + 3].x);
            *(float4*)(d + 12) = make_float4(accB[c0].y, accB[c0 + 1].y,
                                             accB[c0 + 2].y, accB[c0 + 3].y);
        }
    }
    __syncthreads();

    // ---- Stage C: vertical conv (3-tall), b128 quad reads ----
    const int tx = tid & 31;
    const int r0 = (tid >> 5) * 3;        // 0,3,...,15

    v4f sv[2][3];
    #pragma unroll
    for (int q = 0; q < 2; ++q)
        #pragma unroll
        for (int j = 0; j < 3; ++j) sv[q][j] = (v4f)0.0f;

    int base = r0 * RSTRIDE + tx * 4;
    #pragma unroll
    for (int dy = 0; dy < 9; ++dy) {
        const v4f p0 = *(const v4f*)&hbuf[base];
        const v4f p1v = *(const v4f*)&hbuf[base + QSTRIDE];
        #pragma unroll
        for (int j = 0; j < 3; ++j) {
            const int dd = dy - j;
            if (dd >= 0 && dd < 7) {
                const float wg = g[dd];
                sv[0][j] += wg * p0;
                sv[1][j] += wg * p1v;
            }
        }
        base += RSTRIDE;
    }

    float lsum = 0.0f;
    #pragma unroll
    for (int j = 0; j < 3; ++j) {
        if (ys0 + r0 + j < H) {
            const float mu1 = sv[0][j].x, mu2 = sv[0][j].y;
            const float mu3 = sv[0][j].z, E11 = sv[0][j].w;
            const float E22 = sv[1][j].x, E33 = sv[1][j].y;
            const float E12 = sv[1][j].z, E13 = sv[1][j].w;
            const float sig1  = E11 - mu1 * mu1;
            const float sig2  = E22 - mu2 * mu2;
            const float sig3  = E33 - mu3 * mu3;
            const float sig12 = E12 - mu1 * mu2;
            const float sig13 = E13 - mu1 * mu3;
            const float C2 = 9.0e-4f;  // 0.03^2
            const float m12 = (2.0f * sig12 + C2) * __builtin_amdgcn_rcpf(sig1 + sig2 + C2);
            const float m13 = (2.0f * sig13 + C2) * __builtin_amdgcn_rcpf(sig1 + sig3 + C2);
            lsum += (mu2 > mu3) ? m12 : m13;
        }
    }

    // ---- Block reduction (deterministic) ----
    #pragma unroll
    for (int o = 32; o > 0; o >>= 1) lsum += __shfl_down(lsum, o, 64);
    if ((tid & 63) == 0) wavesum[tid >> 6] = lsum;
    __syncthreads();
    if (tid == 0) {
        partial[((size_t)blockIdx.z * gridDim.y + blockIdx.y) * gridDim.x + blockIdx.x] =
            wavesum[0] + wavesum[1] + wavesum[2];
    }
}

// Level-1 reduction: 114 blocks x 256 threads, each reduces exactly 256
// contiguous partials via deterministic LDS f64 tree.
__global__ __launch_bounds__(256) void ssim_reduce1(
    const float* __restrict__ partial, double* __restrict__ p2)
{
    __shared__ double sh[256];
    const int t = threadIdx.x;
    sh[t] = (double)partial[blockIdx.x * 256 + t];
    __syncthreads();
    #pragma unroll
    for (int o = 128; o > 0; o >>= 1) {
        if (t < o) sh[t] += sh[t + o];
        __syncthreads();
    }
    if (t == 0) p2[blockIdx.x] = sh[0];
}

// Level-2: one block sums the 114 doubles (fixed order) and writes the mean.
__global__ __launch_bounds__(128) void ssim_reduce2(
    const double* __restrict__ p2, float* __restrict__ out)
{
    __shared__ double sh[128];
    const int t = threadIdx.x;
    sh[t] = (t < NRED1) ? p2[t] : 0.0;
    __syncthreads();
    #pragma unroll
    for (int o = 64; o > 0; o >>= 1) {
        if (t < o) sh[t] += sh[t + o];
        __syncthreads();
    }
    if (t == 0) out[0] = (float)(sh[0] / (double)((size_t)NB * W * H));
}

extern "C" void kernel_launch(void* const* d_in, const int* in_sizes, int n_in,
                              void* d_out, int out_size, void* d_ws, size_t ws_size,
                              hipStream_t stream) {
    const float* img1 = (const float*)d_in[0];
    const float* img2 = (const float*)d_in[1];
    const float* img3 = (const float*)d_in[2];
    const float* win  = (const float*)d_in[3];
    float* out = (float*)d_out;
    float* partial = (float*)d_ws;                                   // NBLK floats
    double* p2 = (double*)((char*)d_ws + (size_t)NBLK * 4);          // 8B-aligned

    dim3 grid(W / TX, YBLK, NB);  // 32 x 57 x 16 = 29184 blocks
    ssim_main<<<grid, NTH, 0, stream>>>(img1, img2, img3, win, partial);
    ssim_reduce1<<<NRED1, 256, 0, stream>>>(partial, p2);
    ssim_reduce2<<<1, 128, 0, stream>>>(p2, out);
}

// Round 17
// 103.583 us; speedup vs baseline: 1.0487x; 1.0487x over previous
//
#include <hip/hip_runtime.h>

typedef float v2f __attribute__((ext_vector_type(2)));

#define W 1024
#define H 1024
#define NB 16
#define TX 32
#define TY 18
#define HR 24               // TY + 6 h-conv rows per block
#define NTH 192             // 3 waves
#define YBLK ((H + TY - 1) / TY)   // 57 (last block 2 rows OOB, guarded)
#define RSTRIDE (8 * TX)    // dwords per h-row: 8 channels x 32 cols
#define NBLK (32 * YBLK * NB)      // 29184 partials = 114 * 256 exactly
#define NRED1 (NBLK / 256)         // 114 level-1 blocks

// Fused SSIM (r6 structure, verbatim; launch_bounds 4->5 waves/EU to allow
// 6 resident blocks/CU — LDS 25088B x 6 = 150KB <= 160KB, VGPR 48 <= 102).
//   hbuf layout: [HR][8 channels][TX] floats — the measured conflict-free one.
//   Stage B: 192 tasks = 24 rows x 8 col-groups, one per thread; weight-pair
//            m-loop (schedule-sensitive: r14's reorder regressed; keep verbatim).
//   Stage C: 32 cols x 6 rowgroups x 3-tall vertical conv + SSIM map.
__global__ __launch_bounds__(NTH, 5) void ssim_main(
    const float* __restrict__ img1, const float* __restrict__ img2,
    const float* __restrict__ img3, const float* __restrict__ win,
    float* __restrict__ partial)
{
    __shared__ __align__(16) float hbuf[HR * RSTRIDE];  // 24576 B
    __shared__ float wavesum[3];

    const int tid = threadIdx.x;
    const int x0  = blockIdx.x * TX;
    const int ys0 = blockIdx.y * TY;
    const size_t imoff = (size_t)blockIdx.z * (size_t)(W * H);
    const float* p1 = img1 + imoff;
    const float* p2 = img2 + imoff;
    const float* p3 = img3 + imoff;

    // Separable 1-D gaussian: g[j] = win[3][j] / sqrt(win[3][3])
    float g[7];
    {
        const float inv = 1.0f / sqrtf(win[24]);
        #pragma unroll
        for (int j = 0; j < 7; ++j) g[j] = win[21 + j] * inv;
    }

    // ---- Stage B: horizontal conv, global -> LDS (1 task per thread) ----
    {
        const int br  = tid >> 3;            // 0..23  h-row within block
        const int bc0 = (tid & 7) << 2;      // 0,4,...,28
        const int gy  = ys0 + br - 3;
        const int gx0 = x0 + bc0 - 4;
        const bool xfast = (gx0 >= 0) & (gx0 + 12 <= W);

        v2f accA[8], accB[8];                // j=(0,1) and j=(2,3)
        #pragma unroll
        for (int ch = 0; ch < 8; ++ch) { accA[ch] = (v2f)0.0f; accB[ch] = (v2f)0.0f; }

        if ((gy >= 0) & (gy < H)) {
            const size_t rowoff = (size_t)gy * W;
            float V1[12], V2[12], V3[12];
            if (xfast) {
                const float* q1 = p1 + rowoff + gx0;
                const float* q2 = p2 + rowoff + gx0;
                const float* q3 = p3 + rowoff + gx0;
                *(float4*)&V1[0] = *(const float4*)(q1);
                *(float4*)&V1[4] = *(const float4*)(q1 + 4);
                *(float4*)&V1[8] = *(const float4*)(q1 + 8);
                *(float4*)&V2[0] = *(const float4*)(q2);
                *(float4*)&V2[4] = *(const float4*)(q2 + 4);
                *(float4*)&V2[8] = *(const float4*)(q2 + 8);
                *(float4*)&V3[0] = *(const float4*)(q3);
                *(float4*)&V3[4] = *(const float4*)(q3 + 4);
                *(float4*)&V3[8] = *(const float4*)(q3 + 8);
            } else {
                #pragma unroll
                for (int c = 0; c < 12; ++c) {
                    const int x = gx0 + c;
                    const bool ok = (x >= 0) & (x < W);
                    const size_t off = rowoff + x;
                    V1[c] = ok ? p1[off] : 0.0f;
                    V2[c] = ok ? p2[off] : 0.0f;
                    V3[c] = ok ? p3[off] : 0.0f;
                }
            }

            // weight-pair table: gp[m-1] = {g[m-1], g[m-2]} (edges zero-padded)
            v2f gp[8];
            gp[0] = (v2f){g[0], 0.0f};
            #pragma unroll
            for (int m = 2; m <= 7; ++m) gp[m - 1] = (v2f){g[m - 1], g[m - 2]};
            gp[7] = (v2f){0.0f, g[6]};

            #pragma unroll
            for (int m = 1; m <= 8; ++m) {
                const v2f w = gp[m - 1];
                const float vA1 = V1[m], vA2 = V2[m], vA3 = V3[m];
                const float vB1 = V1[m + 2], vB2 = V2[m + 2], vB3 = V3[m + 2];
                v2f t;
                t = w * vA1;
                accA[0] += t;
                accA[3] += t * vA1;
                accA[6] += t * vA2;
                accA[7] += t * vA3;
                t = w * vA2;
                accA[1] += t;
                accA[4] += t * vA2;
                t = w * vA3;
                accA[2] += t;
                accA[5] += t * vA3;
                t = w * vB1;
                accB[0] += t;
                accB[3] += t * vB1;
                accB[6] += t * vB2;
                accB[7] += t * vB3;
                t = w * vB2;
                accB[1] += t;
                accB[4] += t * vB2;
                t = w * vB3;
                accB[2] += t;
                accB[5] += t * vB3;
            }
        }
        const int wbase = br * RSTRIDE + bc0;
        #pragma unroll
        for (int ch = 0; ch < 8; ++ch) {
            *(v2f*)&hbuf[wbase + ch * TX]     = accA[ch];
            *(v2f*)&hbuf[wbase + ch * TX + 2] = accB[ch];
        }
    }
    __syncthreads();

    // ---- Stage C: vertical conv (3-tall), packed across channel pairs ----
    const int tx = tid & 31;
    const int r0 = (tid >> 5) * 3;        // 0,3,...,15

    v2f sv[4][3];
    #pragma unroll
    for (int cp = 0; cp < 4; ++cp)
        #pragma unroll
        for (int j = 0; j < 3; ++j) sv[cp][j] = (v2f)0.0f;

    int base = r0 * RSTRIDE + tx;
    #pragma unroll
    for (int dy = 0; dy < 9; ++dy) {
        v2f p[4];
        #pragma unroll
        for (int cp = 0; cp < 4; ++cp) {
            p[cp].x = hbuf[base + cp * 64];       // channel 2cp
            p[cp].y = hbuf[base + cp * 64 + 32];  // channel 2cp+1
        }
        #pragma unroll
        for (int j = 0; j < 3; ++j) {
            const int dd = dy - j;
            if (dd >= 0 && dd < 7) {
                const float wg = g[dd];
                #pragma unroll
                for (int cp = 0; cp < 4; ++cp) sv[cp][j] += wg * p[cp];
            }
        }
        base += RSTRIDE;
    }

    float lsum = 0.0f;
    #pragma unroll
    for (int j = 0; j < 3; ++j) {
        if (ys0 + r0 + j < H) {
            const float mu1 = sv[0][j].x, mu2 = sv[0][j].y;
            const float mu3 = sv[1][j].x, E11 = sv[1][j].y;
            const float E22 = sv[2][j].x, E33 = sv[2][j].y;
            const float E12 = sv[3][j].x, E13 = sv[3][j].y;
            const float sig1  = E11 - mu1 * mu1;
            const float sig2  = E22 - mu2 * mu2;
            const float sig3  = E33 - mu3 * mu3;
            const float sig12 = E12 - mu1 * mu2;
            const float sig13 = E13 - mu1 * mu3;
            const float C2 = 9.0e-4f;  // 0.03^2
            const float m12 = (2.0f * sig12 + C2) * __builtin_amdgcn_rcpf(sig1 + sig2 + C2);
            const float m13 = (2.0f * sig13 + C2) * __builtin_amdgcn_rcpf(sig1 + sig3 + C2);
            lsum += (mu2 > mu3) ? m12 : m13;
        }
    }

    // ---- Block reduction (deterministic) ----
    #pragma unroll
    for (int o = 32; o > 0; o >>= 1) lsum += __shfl_down(lsum, o, 64);
    if ((tid & 63) == 0) wavesum[tid >> 6] = lsum;
    __syncthreads();
    if (tid == 0) {
        partial[((size_t)blockIdx.z * gridDim.y + blockIdx.y) * gridDim.x + blockIdx.x] =
            wavesum[0] + wavesum[1] + wavesum[2];
    }
}

// Level-1 reduction: 114 blocks x 256 threads, each reduces exactly 256
// contiguous partials via deterministic LDS f64 tree.
__global__ __launch_bounds__(256) void ssim_reduce1(
    const float* __restrict__ partial, double* __restrict__ p2)
{
    __shared__ double sh[256];
    const int t = threadIdx.x;
    sh[t] = (double)partial[blockIdx.x * 256 + t];
    __syncthreads();
    #pragma unroll
    for (int o = 128; o > 0; o >>= 1) {
        if (t < o) sh[t] += sh[t + o];
        __syncthreads();
    }
    if (t == 0) p2[blockIdx.x] = sh[0];
}

// Level-2: one block sums the 114 doubles (fixed order) and writes the mean.
__global__ __launch_bounds__(128) void ssim_reduce2(
    const double* __restrict__ p2, float* __restrict__ out)
{
    __shared__ double sh[128];
    const int t = threadIdx.x;
    sh[t] = (t < NRED1) ? p2[t] : 0.0;
    __syncthreads();
    #pragma unroll
    for (int o = 64; o > 0; o >>= 1) {
        if (t < o) sh[t] += sh[t + o];
        __syncthreads();
    }
    if (t == 0) out[0] = (float)(sh[0] / (double)((size_t)NB * W * H));
}

extern "C" void kernel_launch(void* const* d_in, const int* in_sizes, int n_in,
                              void* d_out, int out_size, void* d_ws, size_t ws_size,
                              hipStream_t stream) {
    const float* img1 = (const float*)d_in[0];
    const float* img2 = (const float*)d_in[1];
    const float* img3 = (const float*)d_in[2];
    const float* win  = (const float*)d_in[3];
    float* out = (float*)d_out;
    float* partial = (float*)d_ws;                                   // NBLK floats
    double* p2 = (double*)((char*)d_ws + (size_t)NBLK * 4);          // 8B-aligned

    dim3 grid(W / TX, YBLK, NB);  // 32 x 57 x 16 = 29184 blocks
    ssim_main<<<grid, NTH, 0, stream>>>(img1, img2, img3, win, partial);
    ssim_reduce1<<<NRED1, 256, 0, stream>>>(partial, p2);
    ssim_reduce2<<<1, 128, 0, stream>>>(p2, out);
}